// Round 2
// baseline (138028.662 us; speedup 1.0000x reference)
//
#include <hip/hip_runtime.h>
#include <hip/hip_fp16.h>
#include <math.h>

#define HID   800
#define FOURH 3200
#define DIN0  42
#define ALPH  20
#define SEQL  700
#define TWOH  1600

__device__ __forceinline__ float sigm(float x) { return 1.0f / (1.0f + __expf(-x)); }
__device__ __forceinline__ float tanh_(float x) { return 1.0f - 2.0f / (1.0f + __expf(2.0f * x)); }

// ---------------------------------------------------------------------------
// LSTM step: one launch = one time step, both directions (blockIdx.y).
// Block = 1024 threads: thread = (g, jj, b); g = gate (i,f,g,o), j = HID row,
// b = batch lane. Each thread computes ONE gate-row dot; gates combined in LDS.
// Hidden state stored fp16, [t][1600][b] (b innermost); cell state fp32.
// MODE 0: layer 0 (fuse x @ Wih, D=42)
// MODE 1: layer 1, read precomputed pre (fp16)      [tier A]
// MODE 2: layer 1, fuse h1 @ Wih1 (K=1600)          [tier B/C]
// TMUL 1: hprev/hout indexed by t;  TMUL 0: ring slots (host pre-offsets ptr)
// ---------------------------------------------------------------------------
template <int MODE, int TMUL>
__global__ __launch_bounds__(1024) void lstm_step(
    int s,
    const float*  __restrict__ xf,
    const __half* __restrict__ xh,
    const __half* __restrict__ pre_f, const __half* __restrict__ pre_r,
    const float* __restrict__ Wih_f, const float* __restrict__ Wih_r,
    const float* __restrict__ Whh_f, const float* __restrict__ Whh_r,
    const float* __restrict__ bias_f, const float* __restrict__ bias_r,
    const __half* __restrict__ hprev, __half* __restrict__ hout,
    float* __restrict__ cbuf)
{
    const int dir = blockIdx.y;
    const int tid = threadIdx.x;
    const int b  = tid & 31;
    const int jj = (tid >> 5) & 7;
    const int g  = tid >> 8;
    const int j  = blockIdx.x * 8 + jj;
    const int row = g * HID + j;
    const int t = dir ? (SEQL - 1 - s) : s;

    __shared__ float xs[DIN0 * 32];
    __shared__ float gv[3][256];

    float acc = (dir ? bias_r : bias_f)[row];

    if constexpr (MODE == 0) {
        for (int e = tid; e < DIN0 * 32; e += 1024) {
            int bb = e / DIN0, kk = e - bb * DIN0;
            xs[kk * 32 + bb] = xf[(size_t)bb * (SEQL * DIN0) + (size_t)t * DIN0 + kk];
        }
        __syncthreads();
        const float* wi = (dir ? Wih_r : Wih_f) + (size_t)row * DIN0;
        #pragma unroll 7
        for (int k = 0; k < DIN0; ++k) acc += wi[k] * xs[k * 32 + b];
    }
    if constexpr (MODE == 1) {
        const __half* pre = dir ? pre_r : pre_f;
        acc += __half2float(pre[((size_t)t * FOURH + row) * 32 + b]);
    }
    if constexpr (MODE == 2) {
        const __half* xp = xh + (size_t)t * (TWOH * 32) + b;
        const float* wi = (dir ? Wih_r : Wih_f) + (size_t)row * TWOH;
        #pragma unroll 2
        for (int k = 0; k < TWOH; k += 4) {
            float4 w = *(const float4*)(wi + k);
            acc += w.x * __half2float(xp[(k + 0) * 32]) + w.y * __half2float(xp[(k + 1) * 32])
                 + w.z * __half2float(xp[(k + 2) * 32]) + w.w * __half2float(xp[(k + 3) * 32]);
        }
    }
    if (s > 0) {
        const int tprev = dir ? t + 1 : t - 1;
        const __half* hp = hprev + ((size_t)(TMUL ? tprev * TWOH : 0) + (size_t)dir * HID) * 32 + b;
        const float* wh = (dir ? Whh_r : Whh_f) + (size_t)row * HID;
        #pragma unroll 2
        for (int k = 0; k < HID; k += 4) {
            float4 w = *(const float4*)(wh + k);
            acc += w.x * __half2float(hp[(k + 0) * 32]) + w.y * __half2float(hp[(k + 1) * 32])
                 + w.z * __half2float(hp[(k + 2) * 32]) + w.w * __half2float(hp[(k + 3) * 32]);
        }
    }

    if (g > 0) gv[g - 1][tid & 255] = acc;
    __syncthreads();
    if (g == 0) {
        float i_ = sigm(acc);
        float f_ = sigm(gv[0][tid]);
        float gg = tanh_(gv[1][tid]);
        float o_ = sigm(gv[2][tid]);
        float* cp = cbuf + ((size_t)dir * HID + j) * 32 + b;
        float c = f_ * (*cp) + i_ * gg;   // cbuf zeroed at call start; s==0 reads 0
        *cp = c;
        float h = o_ * tanh_(c);
        hout[((size_t)(TMUL ? t * TWOH : 0) + (size_t)dir * HID + j) * 32 + b] = __float2half(h);
    }
}

// ---------------------------------------------------------------------------
// pre[dir][t][n][b] = sum_k h1[t][k][b] * Wih1[n][k]  (fp32 math, fp16 I/O)
// M = 22400 (t*32+b), N = 3200, K = 1600. 64x64 tile, K-tile 16, 4x4/thread.
// ---------------------------------------------------------------------------
__global__ __launch_bounds__(256) void gemm_pre1(
    const __half* __restrict__ h1,
    const float* __restrict__ W_f, const float* __restrict__ W_r,
    __half* __restrict__ pre_f, __half* __restrict__ pre_r)
{
    const float* W = blockIdx.z ? W_r : W_f;
    __half* C = blockIdx.z ? pre_r : pre_f;
    __shared__ float As[16][64];
    __shared__ float Bs[16][68];
    const int tid = threadIdx.x;
    const int m4 = (tid >> 4) * 4;
    const int n4 = (tid & 15) * 4;
    const int bm = blockIdx.x * 64;
    const int bn = blockIdx.y * 64;
    float acc[4][4] = {{0.f}};

    for (int k0 = 0; k0 < TWOH; k0 += 16) {
        #pragma unroll
        for (int l = 0; l < 4; ++l) {
            int e = tid + l * 256;
            int k = e >> 6, m = e & 63;
            int gm = bm + m;
            As[k][m] = __half2float(h1[(size_t)(gm >> 5) * (TWOH * 32) + (size_t)(k0 + k) * 32 + (gm & 31)]);
        }
        #pragma unroll
        for (int l = 0; l < 4; ++l) {
            int e = tid + l * 256;
            int k = e & 15, n = e >> 4;
            Bs[k][n] = W[(size_t)(bn + n) * TWOH + k0 + k];
        }
        __syncthreads();
        #pragma unroll
        for (int k = 0; k < 16; ++k) {
            float4 a = *(const float4*)&As[k][m4];
            float4 bv = *(const float4*)&Bs[k][n4];
            float ar[4] = {a.x, a.y, a.z, a.w};
            float br[4] = {bv.x, bv.y, bv.z, bv.w};
            #pragma unroll
            for (int i = 0; i < 4; ++i)
                #pragma unroll
                for (int q = 0; q < 4; ++q)
                    acc[i][q] += ar[i] * br[q];
        }
        __syncthreads();
    }
    #pragma unroll
    for (int i = 0; i < 4; ++i) {
        int gm = bm + m4 + i;
        int tt = gm >> 5, bb = gm & 31;
        __half* cp = C + (size_t)tt * ((size_t)FOURH * 32) + (size_t)(bn + n4) * 32 + bb;
        cp[0]  = __float2half(acc[i][0]);
        cp[32] = __float2half(acc[i][1]);
        cp[64] = __float2half(acc[i][2]);
        cp[96] = __float2half(acc[i][3]);
    }
}

// logits[l][a][b] = blin[a] + sum_k out1[l][k][b] * Wlin[a][k]   (tiers A/B)
__global__ __launch_bounds__(256) void logits_kernel(
    const __half* __restrict__ out1, const float* __restrict__ Wlin,
    const float* __restrict__ blin, float* __restrict__ logits)
{
    const int l = blockIdx.x;
    const int b = threadIdx.x & 31;
    const int a0 = threadIdx.x >> 5;
    const __half* xp = out1 + (size_t)l * (TWOH * 32) + b;
    for (int a = a0; a < ALPH; a += 8) {
        const float* w = Wlin + (size_t)a * TWOH;
        float acc = blin[a];
        #pragma unroll 2
        for (int k = 0; k < TWOH; k += 4) {
            float4 wv = *(const float4*)(w + k);
            acc += wv.x * __half2float(xp[(k + 0) * 32]) + wv.y * __half2float(xp[(k + 1) * 32])
                 + wv.z * __half2float(xp[(k + 2) * 32]) + wv.w * __half2float(xp[(k + 3) * 32]);
        }
        logits[(size_t)l * 640 + (size_t)a * 32 + b] = acc;
    }
}

// ---- tier C: logits = blin, then accumulate per step from hidden ring ----
__global__ __launch_bounds__(640) void logits_init(const float* __restrict__ blin,
                                                   float* __restrict__ logits)
{
    logits[(size_t)blockIdx.x * 640 + threadIdx.x] = blin[threadIdx.x >> 5];
}

__global__ __launch_bounds__(640) void logits_acc(
    int s, const __half* __restrict__ hslot, const float* __restrict__ Wlin,
    float* __restrict__ logits)
{
    const int dir = blockIdx.x;
    const int t = dir ? (SEQL - 1 - s) : s;
    const int a = threadIdx.x >> 5;
    const int b = threadIdx.x & 31;
    const __half* hs = hslot + (size_t)dir * HID * 32 + b;
    const float* w = Wlin + (size_t)a * TWOH + (size_t)dir * HID;
    float acc = 0.f;
    #pragma unroll 4
    for (int k = 0; k < HID; ++k) acc += __half2float(hs[k * 32]) * w[k];
    logits[(size_t)t * 640 + (size_t)a * 32 + b] += acc;
}

// softmax over batch (dim=1) per (l,a); then prob-weighted sin/cos -> pts
__global__ __launch_bounds__(64) void softmax_pts(
    const float* __restrict__ logits, const float* __restrict__ alpha,
    float* __restrict__ pts)
{
    const int l = blockIdx.x;
    const int tid = threadIdx.x;
    const int b = tid & 31;
    float sins[3] = {0.f, 0.f, 0.f}, coss[3] = {0.f, 0.f, 0.f};
    for (int a = 0; a < ALPH; ++a) {
        float v = logits[(size_t)l * 640 + (size_t)a * 32 + b];
        float m = v;
        #pragma unroll
        for (int d = 16; d >= 1; d >>= 1) m = fmaxf(m, __shfl_xor(m, d));
        float e = __expf(v - m);
        float ssum = e;
        #pragma unroll
        for (int d = 16; d >= 1; d >>= 1) ssum += __shfl_xor(ssum, d);
        float pv = e / ssum;
        #pragma unroll
        for (int d = 0; d < 3; ++d) {
            float ang = alpha[a * 3 + d];
            sins[d] += pv * sinf(ang);
            coss[d] += pv * cosf(ang);
        }
    }
    if (tid < 32) {
        const float blen[3] = {145.801f, 152.326f, 132.868f};
        const float bang[3] = {2.124f, 1.941f, 2.028f};
        #pragma unroll
        for (int d = 0; d < 3; ++d) {
            float pa = 3.14159265358979323846f - bang[d];
            float rsin = blen[d] * sinf(pa);
            float sv = sins[d], cv = coss[d];
            float den = sqrtf(sv * sv + cv * cv);
            float cs, sn;
            if (den > 0.f) { cs = cv / den; sn = sv / den; }
            else           { cs = 1.f;     sn = 0.f; }
            size_t m = (size_t)(3 * l + d);
            pts[m * 64 + b]      = cs * rsin;  // py
            pts[m * 64 + 32 + b] = sn * rsin;  // pz
        }
    }
}

// NeRF chain: 32 independent batch chains, lockstep in one wave
__global__ __launch_bounds__(64) void coords_kernel(
    const float* __restrict__ pts, float* __restrict__ out)
{
    const int tid = threadIdx.x;
    const int b = tid & 31;
    float ax = -0.70710678118654752f, ay = 1.22474487139158905f, az = 0.f;
    float bx = -1.41421356237309505f, by = 0.f, bz = 0.f;
    float cx = 0.f, cy = 0.f, cz = 0.f;
    const float blen[3] = {145.801f, 152.326f, 132.868f};
    const float bang[3] = {2.124f, 1.941f, 2.028f};
    float rcos[3];
    #pragma unroll
    for (int d = 0; d < 3; ++d)
        rcos[d] = blen[d] * cosf(3.14159265358979323846f - bang[d]);

    int j = 0;
    for (int m = 0; m < 3 * SEQL; ++m) {
        float px = rcos[j];
        float py = pts[(size_t)m * 64 + b];
        float pz = pts[(size_t)m * 64 + 32 + b];
        float ux = cx - bx, uy = cy - by, uz = cz - bz;
        float inv = rsqrtf(ux * ux + uy * uy + uz * uz + 1e-12f);
        ux *= inv; uy *= inv; uz *= inv;
        float vx = bx - ax, vy = by - ay, vz = bz - az;
        float nx = vy * uz - vz * uy;
        float ny = vz * ux - vx * uz;
        float nz = vx * uy - vy * ux;
        float inv2 = rsqrtf(nx * nx + ny * ny + nz * nz + 1e-12f);
        nx *= inv2; ny *= inv2; nz *= inv2;
        float mx = ny * uz - nz * uy;
        float my = nz * ux - nx * uz;
        float mz = nx * uy - ny * ux;
        float ox = cx + ux * px + mx * py + nx * pz;
        float oy = cy + uy * px + my * py + ny * pz;
        float oz = cz + uz * px + mz * py + nz * pz;
        if (tid < 32) {
            float* o = out + ((size_t)m * 32 + b) * 3;
            o[0] = ox; o[1] = oy; o[2] = oz;
        }
        ax = bx; ay = by; az = bz;
        bx = cx; by = cy; bz = cz;
        cx = ox; cy = oy; cz = oz;
        j = (j == 2) ? 0 : j + 1;
    }
}

// ---------------------------------------------------------------------------
extern "C" void kernel_launch(void* const* d_in, const int* in_sizes, int n_in,
                              void* d_out, int out_size, void* d_ws, size_t ws_size,
                              hipStream_t stream)
{
    const float* x     = (const float*)d_in[0];
    const float* Wih0f = (const float*)d_in[1];
    const float* Whh0f = (const float*)d_in[2];
    const float* b0f   = (const float*)d_in[3];
    const float* Wih0r = (const float*)d_in[4];
    const float* Whh0r = (const float*)d_in[5];
    const float* b0r   = (const float*)d_in[6];
    const float* Wih1f = (const float*)d_in[7];
    const float* Whh1f = (const float*)d_in[8];
    const float* b1f   = (const float*)d_in[9];
    const float* Wih1r = (const float*)d_in[10];
    const float* Whh1r = (const float*)d_in[11];
    const float* b1r   = (const float*)d_in[12];
    const float* Wlin  = (const float*)d_in[13];
    const float* blin  = (const float*)d_in[14];
    const float* alpha = (const float*)d_in[15];

    // ---- workspace layout (bytes): smalls 2.944 MB, h1 71.68 MB,
    //      out1 71.68 MB (tier>=B), pre1 286.72 MB (tier A) ----
    float*  cbuf   = (float*)d_ws;            // [2 layers][2 dirs][800][32] fp32
    float*  logits = cbuf + 102400;           // [700][20][32] fp32
    float*  pts    = logits + 448000;         // [2100][2][32] fp32
    __half* hring  = (__half*)(pts + 134400); // [2][1600][32] fp16
    __half* h1     = hring + 102400;          // [700][1600][32] fp16
    __half* out1   = h1 + 35840000;
    __half* pre1f  = out1 + 35840000;         // [700][3200][32] fp16
    __half* pre1r  = pre1f + 71680000;

    const size_t needC = 74624000ull;
    const size_t needB = 146304000ull;
    const size_t needA = 433024000ull;
    if (ws_size < needC) return;  // ws too small for anything -> clean absmax fail (diagnostic)

    const int tier = (ws_size >= needA) ? 0 : (ws_size >= needB) ? 1 : 2;

    hipMemsetAsync(cbuf, 0, 102400 * sizeof(float), stream);

    dim3 sg(100, 2);

    // ---- layer 0 ----
    for (int s = 0; s < SEQL; ++s)
        lstm_step<0, 1><<<sg, 1024, 0, stream>>>(
            s, x, nullptr, nullptr, nullptr,
            Wih0f, Wih0r, Whh0f, Whh0r, b0f, b0r,
            h1, h1, cbuf);

    // ---- layer 1 ----
    if (tier == 0) {
        gemm_pre1<<<dim3(350, 50, 2), 256, 0, stream>>>(h1, Wih1f, Wih1r, pre1f, pre1r);
        for (int s = 0; s < SEQL; ++s)
            lstm_step<1, 1><<<sg, 1024, 0, stream>>>(
                s, nullptr, nullptr, pre1f, pre1r,
                nullptr, nullptr, Whh1f, Whh1r, b1f, b1r,
                out1, out1, cbuf + 51200);
        logits_kernel<<<700, 256, 0, stream>>>(out1, Wlin, blin, logits);
    } else if (tier == 1) {
        for (int s = 0; s < SEQL; ++s)
            lstm_step<2, 1><<<sg, 1024, 0, stream>>>(
                s, nullptr, h1, nullptr, nullptr,
                Wih1f, Wih1r, Whh1f, Whh1r, b1f, b1r,
                out1, out1, cbuf + 51200);
        logits_kernel<<<700, 256, 0, stream>>>(out1, Wlin, blin, logits);
    } else {
        logits_init<<<700, 640, 0, stream>>>(blin, logits);
        for (int s = 0; s < SEQL; ++s) {
            lstm_step<2, 0><<<sg, 1024, 0, stream>>>(
                s, nullptr, h1, nullptr, nullptr,
                Wih1f, Wih1r, Whh1f, Whh1r, b1f, b1r,
                hring + (size_t)((s + 1) & 1) * 51200,
                hring + (size_t)(s & 1) * 51200, cbuf + 51200);
            logits_acc<<<2, 640, 0, stream>>>(s, hring + (size_t)(s & 1) * 51200, Wlin, logits);
        }
    }

    // ---- head ----
    softmax_pts<<<700, 64, 0, stream>>>(logits, alpha, pts);
    coords_kernel<<<1, 64, 0, stream>>>(pts, (float*)d_out);
}

// Round 3
// 38171.432 us; speedup vs baseline: 3.6160x; 3.6160x over previous
//
#include <hip/hip_runtime.h>
#include <math.h>

#define HID   800
#define ALPH  20
#define SEQL  700
#define TWOH  1600

typedef _Float16 f16;
typedef _Float16 f16x8 __attribute__((ext_vector_type(8)));
typedef float    f32x4 __attribute__((ext_vector_type(4)));

__device__ __forceinline__ float sigm(float x) { return 1.0f / (1.0f + __expf(-x)); }
__device__ __forceinline__ float tanh_(float x) { return 1.0f - 2.0f / (1.0f + __expf(2.0f * x)); }

// Device-wide barrier: monotonic counter, one atomic per block per step.
// Grid <= 256 blocks of 512 thr => all co-resident (8 waves/CU <= 32).
__device__ __forceinline__ void gbar(unsigned* bar, unsigned target) {
    __syncthreads();
    if (threadIdx.x == 0) {
        __threadfence();
        __hip_atomic_fetch_add(bar, 1u, __ATOMIC_ACQ_REL, __HIP_MEMORY_SCOPE_AGENT);
        while (__hip_atomic_load(bar, __ATOMIC_ACQUIRE, __HIP_MEMORY_SCOPE_AGENT) < target)
            __builtin_amdgcn_s_sleep(2);
        __threadfence();
    }
    __syncthreads();
}

// x [B=32][L=700][42] f32  ->  xT [t][b][64] f16 (zero-padded 42->64)
__global__ __launch_bounds__(256) void transpose_x(const float* __restrict__ x,
                                                   f16* __restrict__ xT) {
    const int t = blockIdx.x;
    const int b = threadIdx.x >> 3;
    const int kc = (threadIdx.x & 7) * 8;
    #pragma unroll
    for (int e = 0; e < 8; ++e) {
        int k = kc + e;
        float v = (k < 42) ? x[((size_t)b * SEQL + t) * 42 + k] : 0.f;
        xT[(size_t)t * 2048 + b * 64 + k] = (f16)v;
    }
}

// ---------------------------------------------------------------------------
// Persistent LSTM layer. Weight-stationary MFMA (fp16 A-frags in VGPRs).
// Row-tile = 16 rows = 4 j x 4 gates (interleaved at A-load) x 32 batches.
// LAYER 0: 100 blocks (50/dir), 4 tiles x 2 K-waves per block; K = 64(x)+800(h).
// LAYER 1: 200 main blocks (100/dir), 2 tiles x 4 K-waves; K = 1600(h1)+800(h);
//          + 10 logits blocks consuming the h-ring one step behind.
// Layouts: h1 [t][b][1600] f16; ring [slot2][dir2][b][800] f16; c in LDS.
// ---------------------------------------------------------------------------
template <int LAYER>
__global__ __launch_bounds__(512) void lstm_phase(
    const float* __restrict__ Wih_f, const float* __restrict__ Wih_r,
    const float* __restrict__ Whh_f, const float* __restrict__ Whh_r,
    const float* __restrict__ bias_f, const float* __restrict__ bias_r,
    const f16* __restrict__ xT,
    f16* __restrict__ h1,
    f16* __restrict__ ring,
    float* __restrict__ logits,
    const float* __restrict__ Wlin, const float* __restrict__ blin,
    unsigned* __restrict__ bar)
{
    constexpr int TPB    = (LAYER == 0) ? 4 : 2;    // row-tiles per block
    constexpr int KWAVES = (LAYER == 0) ? 2 : 4;    // K-split waves per tile
    constexpr int KF     = (LAYER == 0) ? 14 : 19;  // frags per wave (incl pad)
    constexpr int BPD    = (LAYER == 0) ? 50 : 100; // main blocks per dir
    constexpr int NMAIN  = (LAYER == 0) ? 100 : 200;
    constexpr int NIN_F  = (LAYER == 0) ? 2 : 50;   // input-projection frags
    constexpr int NTOT_F = (LAYER == 0) ? 27 : 75;  // valid frags (rest pad)
    constexpr int SMAX   = (LAYER == 0) ? 699 : 700;
    constexpr int PER_T  = TPB * 16 * 32 / 512;     // preacts per thread

    __shared__ float lds_part[TPB * KWAVES][2][16][16];
    __shared__ float lds_pre[TPB][16][32];
    __shared__ float lds_c[TPB][4][32];

    const int bid = blockIdx.x, tid = threadIdx.x;
    const int lane = tid & 63, wid = tid >> 6;
    const unsigned nblocks = gridDim.x;
    const bool is_main = (LAYER == 0) || (bid < NMAIN);

    int dir = 0, tb = 0, kw = 0, kg8 = 0;
    f16x8 areg[KF];
    float biasreg[PER_T];

    if (is_main) {
        dir = bid / BPD;
        tb  = bid % BPD;
        const int tile_sel = wid / KWAVES;
        kw = wid % KWAVES;
        const int row_local = lane & 15;
        const int gate = row_local >> 2, jl = row_local & 3;
        const int jtile = tb * TPB + tile_sel;
        const int grow = gate * HID + jtile * 4 + jl;   // interleaved gate row
        kg8 = (lane >> 4) * 8;
        const float* Wih = dir ? Wih_r : Wih_f;
        const float* Whh = dir ? Whh_r : Whh_f;

        #pragma unroll
        for (int fi = 0; fi < KF; ++fi) {
            int kf = kw * KF + fi;
            f16x8 a{};
            if constexpr (LAYER == 0) {
                if (kf < NIN_F) {
                    int k0 = kf * 32 + kg8;
                    #pragma unroll
                    for (int e = 0; e < 8; ++e) {
                        int k = k0 + e;
                        a[e] = (f16)((k < 42) ? Wih[(size_t)grow * 42 + k] : 0.f);
                    }
                } else if (kf < NTOT_F) {
                    const float* p = Whh + (size_t)grow * HID + (kf - NIN_F) * 32 + kg8;
                    #pragma unroll
                    for (int e = 0; e < 8; ++e) a[e] = (f16)p[e];
                }
            } else {
                if (kf < NIN_F) {
                    const float* p = Wih + (size_t)grow * TWOH + kf * 32 + kg8;
                    #pragma unroll
                    for (int e = 0; e < 8; ++e) a[e] = (f16)p[e];
                } else if (kf < NTOT_F) {
                    const float* p = Whh + (size_t)grow * HID + (kf - NIN_F) * 32 + kg8;
                    #pragma unroll
                    for (int e = 0; e < 8; ++e) a[e] = (f16)p[e];
                }
            }
            areg[fi] = a;
        }

        const float* bias = dir ? bias_r : bias_f;
        #pragma unroll
        for (int i = 0; i < PER_T; ++i) {
            int idx = tid + i * 512;
            int row = (idx >> 5) & 15, tile = idx >> 9;
            int g_ = row >> 2, jl_ = row & 3;
            biasreg[i] = bias[g_ * HID + (tb * TPB + tile) * 4 + jl_];
        }
        if (tid < TPB * 128) {
            int tile = tid >> 7, jl_ = (tid >> 5) & 3, b = tid & 31;
            lds_c[tile][jl_][b] = 0.f;
        }
    }
    __syncthreads();

    for (int s = 0; s <= SMAX; ++s) {
        if (is_main && (LAYER == 0 || s < SEQL)) {
            const int t = dir ? (SEQL - 1 - s) : s;
            const bool rec_ok = (s > 0);
            const f16* srcin;
            const f16* srcrec;
            if constexpr (LAYER == 0) {
                srcin = xT + (size_t)t * 2048;
                int tp = dir ? t + 1 : t - 1;
                if (!rec_ok) tp = 0;
                srcrec = h1 + (size_t)tp * 51200 + dir * HID;
            } else {
                srcin = h1 + (size_t)t * 51200;
                srcrec = ring + ((size_t)((s + 1) & 1) * 2 + dir) * 25600;
            }

            #pragma unroll
            for (int bt = 0; bt < 2; ++bt) {
                const int bcol = bt * 16 + (lane & 15);
                f32x4 acc = {0.f, 0.f, 0.f, 0.f};
                #pragma unroll
                for (int fi = 0; fi < KF; ++fi) {
                    int kf = kw * KF + fi;
                    if constexpr (LAYER == 0) {
                        if (kf < NIN_F) {
                            const f16x8* p = (const f16x8*)(srcin + (size_t)bcol * 64 + kf * 32 + kg8);
                            acc = __builtin_amdgcn_mfma_f32_16x16x32_f16(areg[fi], *p, acc, 0, 0, 0);
                        } else if (kf < NTOT_F && rec_ok) {
                            const f16x8* p = (const f16x8*)(srcrec + (size_t)bcol * TWOH + (kf - NIN_F) * 32 + kg8);
                            acc = __builtin_amdgcn_mfma_f32_16x16x32_f16(areg[fi], *p, acc, 0, 0, 0);
                        }
                    } else {
                        if (kf < NIN_F) {
                            const f16x8* p = (const f16x8*)(srcin + (size_t)bcol * TWOH + kf * 32 + kg8);
                            acc = __builtin_amdgcn_mfma_f32_16x16x32_f16(areg[fi], *p, acc, 0, 0, 0);
                        } else if (kf < NTOT_F && rec_ok) {
                            const f16x8* p = (const f16x8*)(srcrec + (size_t)bcol * HID + (kf - NIN_F) * 32 + kg8);
                            acc = __builtin_amdgcn_mfma_f32_16x16x32_f16(areg[fi], *p, acc, 0, 0, 0);
                        }
                    }
                }
                #pragma unroll
                for (int r = 0; r < 4; ++r)
                    lds_part[wid][bt][(lane >> 4) * 4 + r][lane & 15] = acc[r];
            }
            __syncthreads();

            #pragma unroll
            for (int i = 0; i < PER_T; ++i) {
                int idx = tid + i * 512;
                int b = idx & 31, row = (idx >> 5) & 15, tile = idx >> 9;
                int bt = b >> 4, col = b & 15;
                float sum = biasreg[i];
                #pragma unroll
                for (int k2 = 0; k2 < KWAVES; ++k2)
                    sum += lds_part[tile * KWAVES + k2][bt][row][col];
                lds_pre[tile][row][b] = sum;
            }
            __syncthreads();

            if (tid < TPB * 128) {
                int tile = tid >> 7, jl_ = (tid >> 5) & 3, b = tid & 31;
                float gi = sigm(lds_pre[tile][jl_][b]);
                float gf = sigm(lds_pre[tile][4 + jl_][b]);
                float gg = tanh_(lds_pre[tile][8 + jl_][b]);
                float go = sigm(lds_pre[tile][12 + jl_][b]);
                float c = gf * lds_c[tile][jl_][b] + gi * gg;
                lds_c[tile][jl_][b] = c;
                f16 h = (f16)(go * tanh_(c));
                int jglob = (tb * TPB + tile) * 4 + jl_;
                if constexpr (LAYER == 0)
                    h1[(size_t)t * 51200 + (size_t)b * TWOH + dir * HID + jglob] = h;
                else
                    ring[((size_t)(s & 1) * 2 + dir) * 25600 + (size_t)b * HID + jglob] = h;
            }
        } else if (LAYER == 1 && !is_main) {
            const int lb = bid - NMAIN;  // 0..9
            if (s == 0) {
                for (int idx = lb * 512 + tid; idx < SEQL * 640; idx += 10 * 512)
                    logits[idx] = blin[(idx >> 5) % ALPH];
            } else {
                const int dirL = lb / 5;
                const int tL = dirL ? (SEQL - s) : (s - 1);
                const int a = (lb % 5) * 4 + (tid >> 7);
                const int b = (tid >> 2) & 31;
                const int kc = tid & 3;
                const f16* hs = ring + ((size_t)((s + 1) & 1) * 2 + dirL) * 25600 + (size_t)b * HID + kc * 200;
                const float* wsrc = Wlin + (size_t)a * TWOH + dirL * HID + kc * 200;
                float acc = 0.f;
                #pragma unroll
                for (int q = 0; q < 25; ++q) {
                    f16x8 hv = ((const f16x8*)hs)[q];
                    #pragma unroll
                    for (int e = 0; e < 8; ++e) acc += (float)hv[e] * wsrc[q * 8 + e];
                }
                acc += __shfl_xor(acc, 1);
                acc += __shfl_xor(acc, 2);
                if (kc == 0) logits[(size_t)tL * 640 + a * 32 + b] += acc;
            }
        }
        if (s < SMAX) gbar(bar, nblocks * (unsigned)(s + 1));
    }
}

// softmax over batch (dim=1) per (l,a); prob-weighted sin/cos -> pts [m][2][32]
__global__ __launch_bounds__(64) void softmax_pts(
    const float* __restrict__ logits, const float* __restrict__ alpha,
    float* __restrict__ pts)
{
    const int l = blockIdx.x;
    const int tid = threadIdx.x;
    const int b = tid & 31;
    float sins[3] = {0.f, 0.f, 0.f}, coss[3] = {0.f, 0.f, 0.f};
    for (int a = 0; a < ALPH; ++a) {
        float v = logits[(size_t)l * 640 + (size_t)a * 32 + b];
        float m = v;
        #pragma unroll
        for (int d = 16; d >= 1; d >>= 1) m = fmaxf(m, __shfl_xor(m, d));
        float e = __expf(v - m);
        float ssum = e;
        #pragma unroll
        for (int d = 16; d >= 1; d >>= 1) ssum += __shfl_xor(ssum, d);
        float pv = e / ssum;
        #pragma unroll
        for (int d = 0; d < 3; ++d) {
            float ang = alpha[a * 3 + d];
            sins[d] += pv * sinf(ang);
            coss[d] += pv * cosf(ang);
        }
    }
    if (tid < 32) {
        const float blen[3] = {145.801f, 152.326f, 132.868f};
        const float bang[3] = {2.124f, 1.941f, 2.028f};
        #pragma unroll
        for (int d = 0; d < 3; ++d) {
            float pa = 3.14159265358979323846f - bang[d];
            float rsin = blen[d] * sinf(pa);
            float sv = sins[d], cv = coss[d];
            float den = sqrtf(sv * sv + cv * cv);
            float cs, sn;
            if (den > 0.f) { cs = cv / den; sn = sv / den; }
            else           { cs = 1.f;     sn = 0.f; }
            size_t m = (size_t)(3 * l + d);
            pts[m * 64 + b]      = cs * rsin;
            pts[m * 64 + 32 + b] = sn * rsin;
        }
    }
}

// NeRF chain: 32 independent batch chains in one wave.
// |c-b| == bond length for m>=1 (by construction) -> constant reciprocal.
__global__ __launch_bounds__(64) void coords_kernel(
    const float* __restrict__ pts, float* __restrict__ out)
{
    const int tid = threadIdx.x;
    const int b = tid & 31;
    float ax = -0.70710678118654752f, ay = 1.22474487139158905f, az = 0.f;
    float bx = -1.41421356237309505f, by = 0.f, bz = 0.f;
    float cx = 0.f, cy = 0.f, cz = 0.f;
    const float blen[3] = {145.801f, 152.326f, 132.868f};
    const float bang[3] = {2.124f, 1.941f, 2.028f};
    float rcos[3], rb[3];
    #pragma unroll
    for (int d = 0; d < 3; ++d) {
        rcos[d] = blen[d] * cosf(3.14159265358979323846f - bang[d]);
        rb[d] = 1.0f / blen[d];
    }
    int j = 0;
    for (int m = 0; m < 3 * SEQL; ++m) {
        float px = rcos[j];
        float py = pts[(size_t)m * 64 + b];
        float pz = pts[(size_t)m * 64 + 32 + b];
        float ux = cx - bx, uy = cy - by, uz = cz - bz;         // c - b (unnormalized)
        float inv = (m == 0) ? rsqrtf(ux * ux + uy * uy + uz * uz + 1e-12f)
                             : rb[(j + 2) % 3];
        float vx = bx - ax, vy = by - ay, vz = bz - az;
        float nx = vy * uz - vz * uy;                           // cross(b-a, c-b)
        float ny = vz * ux - vx * uz;
        float nz = vx * uy - vy * ux;
        float inv2 = rsqrtf(nx * nx + ny * ny + nz * nz + 1e-12f);
        nx *= inv2; ny *= inv2; nz *= inv2;
        float mx = ny * uz - nz * uy;                           // cross(n, c-b)
        float my = nz * ux - nx * uz;
        float mz = nx * uy - ny * ux;
        float sx = px * inv, sy = py * inv;                     // fold normalize of bc
        float ox = cx + ux * sx + mx * sy + nx * pz;
        float oy = cy + uy * sx + my * sy + ny * pz;
        float oz = cz + uz * sx + mz * sy + nz * pz;
        if (tid < 32) {
            float* o = out + ((size_t)m * 32 + b) * 3;
            o[0] = ox; o[1] = oy; o[2] = oz;
        }
        ax = bx; ay = by; az = bz;
        bx = cx; by = cy; bz = cz;
        cx = ox; cy = oy; cz = oz;
        j = (j == 2) ? 0 : j + 1;
    }
}

// ---------------------------------------------------------------------------
extern "C" void kernel_launch(void* const* d_in, const int* in_sizes, int n_in,
                              void* d_out, int out_size, void* d_ws, size_t ws_size,
                              hipStream_t stream)
{
    const float* x     = (const float*)d_in[0];
    const float* Wih0f = (const float*)d_in[1];
    const float* Whh0f = (const float*)d_in[2];
    const float* b0f   = (const float*)d_in[3];
    const float* Wih0r = (const float*)d_in[4];
    const float* Whh0r = (const float*)d_in[5];
    const float* b0r   = (const float*)d_in[6];
    const float* Wih1f = (const float*)d_in[7];
    const float* Whh1f = (const float*)d_in[8];
    const float* b1f   = (const float*)d_in[9];
    const float* Wih1r = (const float*)d_in[10];
    const float* Whh1r = (const float*)d_in[11];
    const float* b1r   = (const float*)d_in[12];
    const float* Wlin  = (const float*)d_in[13];
    const float* blin  = (const float*)d_in[14];
    const float* alpha = (const float*)d_in[15];

    // ws layout: [bar 256B][h1 71,680,000B][region 2,867,200B]
    //   region = xT during layer 0; reused as {ring, logits, pts} afterwards.
    if (ws_size < 74547456ull) return;
    unsigned* bar = (unsigned*)d_ws;
    f16* h1 = (f16*)((char*)d_ws + 256);
    char* region = (char*)d_ws + 256 + 71680000ull;
    f16*   xT     = (f16*)region;
    f16*   ring   = (f16*)region;                 // 204,800 B (alias, L1 phase)
    float* logits = (float*)(region + 204800);    // 1,792,000 B
    float* pts    = (float*)(region + 1996800);   // 537,600 B

    hipMemsetAsync(bar, 0, 16, stream);
    transpose_x<<<SEQL, 256, 0, stream>>>(x, xT);
    lstm_phase<0><<<100, 512, 0, stream>>>(
        Wih0f, Wih0r, Whh0f, Whh0r, b0f, b0r,
        xT, h1, ring, logits, Wlin, blin, bar);
    lstm_phase<1><<<210, 512, 0, stream>>>(
        Wih1f, Wih1r, Whh1f, Whh1r, b1f, b1r,
        xT, h1, ring, logits, Wlin, blin, bar + 1);
    softmax_pts<<<SEQL, 64, 0, stream>>>(logits, alpha, pts);
    coords_kernel<<<1, 64, 0, stream>>>(pts, (float*)d_out);
}

// Round 4
// 18582.042 us; speedup vs baseline: 7.4281x; 2.0542x over previous
//
#include <hip/hip_runtime.h>
#include <math.h>

#define HID   800
#define ALPH  20
#define SEQL  700
#define TWOH  1600

typedef _Float16 f16;
typedef _Float16 f16x8 __attribute__((ext_vector_type(8)));
typedef float    f32x4 __attribute__((ext_vector_type(4)));

__device__ __forceinline__ float sigm(float x) { return 1.0f / (1.0f + __expf(-x)); }
__device__ __forceinline__ float tanh_(float x) { return 1.0f - 2.0f / (1.0f + __expf(2.0f * x)); }

// x [B=32][L=700][42] f32  ->  xT [t][b][64] f16 (zero-padded 42->64)
__global__ __launch_bounds__(256) void transpose_x(const float* __restrict__ x,
                                                   f16* __restrict__ xT) {
    const int t = blockIdx.x;
    const int b = threadIdx.x >> 3;
    const int kc = (threadIdx.x & 7) * 8;
    #pragma unroll
    for (int e = 0; e < 8; ++e) {
        int k = kc + e;
        float v = (k < 42) ? x[((size_t)b * SEQL + t) * 42 + k] : 0.f;
        xT[(size_t)t * 2048 + b * 64 + k] = (f16)v;
    }
}

// ---------------------------------------------------------------------------
// Persistent LSTM layer, weight-stationary MFMA.
// Per-dir grid-barrier (relaxed spin + one rel/acq fence pair per step).
// Step schedule: signal -> input-proj MFMAs (overlaps others' arrival) ->
//                spin -> recurrence MFMAs -> reduce/gates -> 16B h store.
// 8 waves/block: wave = (tile_sel<1:0>=wid>>2, kw=wid&3). Tile = 16 rows
// (4 j x 4 gates interleaved) x 32 batch. TPB=2 tiles, 4-way K-split.
// LAYER 0: 200 blocks (100/dir); A = x-proj (K=64), B = Whh (K=800).
// LAYER 1: 200 main (100/dir) + 10 logits blocks; A = Wih1 (K=1600),
//          B = Whh (K=800); h kept in 4-slot ring; logits blocks consume
//          ring one step behind (their own overlap slot).
// ---------------------------------------------------------------------------
template <int LAYER>
__global__ __launch_bounds__(512) void lstm_phase(
    const float* __restrict__ Wih_f, const float* __restrict__ Wih_r,
    const float* __restrict__ Whh_f, const float* __restrict__ Whh_r,
    const float* __restrict__ bias_f, const float* __restrict__ bias_r,
    const f16* __restrict__ xT,
    f16* __restrict__ h1,
    f16* __restrict__ ring,
    float* __restrict__ logits,
    const float* __restrict__ Wlin, const float* __restrict__ blin,
    unsigned* __restrict__ bar)
{
    constexpr int TPB   = 2;
    constexpr int BPD   = 100;
    constexpr int NMAIN = 200;
    constexpr int MAXA  = (LAYER == 0) ? 2 : 13;
    constexpr int MAXB  = 7;
    constexpr int GSIZE = (LAYER == 0) ? 100 : 105;
    constexpr int SMAX  = (LAYER == 0) ? 699 : 700;

    __shared__ float lds_part[8][2][16][16];
    __shared__ float lds_pre[TPB][16][32];
    __shared__ float lds_c[TPB][4][32];
    __shared__ f16   lds_h[TPB * 4][32];

    const int bid = blockIdx.x, tid = threadIdx.x;
    const int lane = tid & 63, wid = tid >> 6;
    const bool is_main = (LAYER == 0) || (bid < NMAIN);

    int dir, tb = 0;
    if (is_main) { dir = bid / BPD; tb = bid % BPD; }
    else         { dir = (bid - NMAIN) / 5; }
    unsigned* mybar = bar + ((LAYER == 0 ? 0 : 2) + dir) * 64;

    const int tile_sel = wid >> 2, kw = wid & 3;
    const int row_local = lane & 15;
    const int kg8 = (lane >> 4) * 8;

    int cntA, offA;
    if constexpr (LAYER == 0) { cntA = (kw == 0) ? 2 : 0; offA = 0; }
    else { cntA = (kw < 2) ? 13 : 12; offA = (kw < 2) ? kw * 13 : 26 + (kw - 2) * 12; }
    const int cntB = (kw == 0) ? 7 : 6;
    const int offB = (kw == 0) ? 0 : 7 + (kw - 1) * 6;

    f16x8 aregA[MAXA];
    f16x8 aregB[MAXB];
    float biasreg[2] = {0.f, 0.f};

    if (is_main) {
        const int gate = row_local >> 2, jl = row_local & 3;
        const int jtile = tb * TPB + tile_sel;
        const int grow = gate * HID + jtile * 4 + jl;
        const float* Wih = dir ? Wih_r : Wih_f;
        const float* Whh = dir ? Whh_r : Whh_f;

        #pragma unroll
        for (int fi = 0; fi < MAXA; ++fi) {
            f16x8 a{};
            if (fi < cntA) {
                int kf = offA + fi;
                if constexpr (LAYER == 0) {
                    int k0 = kf * 32 + kg8;
                    #pragma unroll
                    for (int e = 0; e < 8; ++e)
                        a[e] = (f16)((k0 + e < 42) ? Wih[(size_t)grow * 42 + k0 + e] : 0.f);
                } else {
                    const float* p = Wih + (size_t)grow * TWOH + kf * 32 + kg8;
                    #pragma unroll
                    for (int e = 0; e < 8; ++e) a[e] = (f16)p[e];
                }
            }
            aregA[fi] = a;
        }
        #pragma unroll
        for (int fi = 0; fi < MAXB; ++fi) {
            f16x8 a{};
            if (fi < cntB) {
                const float* p = Whh + (size_t)grow * HID + (offB + fi) * 32 + kg8;
                #pragma unroll
                for (int e = 0; e < 8; ++e) a[e] = (f16)p[e];
            }
            aregB[fi] = a;
        }
        const float* bias = dir ? bias_r : bias_f;
        #pragma unroll
        for (int i = 0; i < 2; ++i) {
            int idx = tid + i * 512;
            int row = (idx >> 5) & 15, tile = idx >> 9;
            biasreg[i] = bias[(row >> 2) * HID + (tb * TPB + tile) * 4 + (row & 3)];
        }
        if (tid < TPB * 128) {
            int tile = tid >> 7, jl_ = (tid >> 5) & 3, b = tid & 31;
            lds_c[tile][jl_][b] = 0.f;
        }
    }
    __syncthreads();

    for (int s = 0; s <= SMAX; ++s) {
        const int t = dir ? (SEQL - 1 - s) : s;
        const bool do_comp = is_main && (LAYER == 0 || s < SEQL);

        // pre-signal: logits base init (must precede arrival #1)
        if (LAYER == 1 && !is_main && s == 0) {
            const int lb = bid - NMAIN;
            for (int idx = lb * 512 + tid; idx < SEQL * 640; idx += 10 * 512)
                logits[idx] = blin[(idx >> 5) % ALPH];
        }
        __syncthreads();   // also drains prev step's h stores (vmcnt)
        if (tid == 0) {
            __builtin_amdgcn_fence(__ATOMIC_RELEASE, "agent");   // wbl2: publish h(s-1)
            __hip_atomic_fetch_add(mybar, 1u, __ATOMIC_RELAXED, __HIP_MEMORY_SCOPE_AGENT);
        }

        // ---- overlapped with other blocks' arrival: input projection ----
        f32x4 acc2[2];
        #pragma unroll
        for (int bt = 0; bt < 2; ++bt) acc2[bt] = {0.f, 0.f, 0.f, 0.f};
        if (do_comp) {
            const f16* srcin = (LAYER == 0) ? (xT + (size_t)t * 2048)
                                            : (h1 + (size_t)t * 51200);
            #pragma unroll
            for (int bt = 0; bt < 2; ++bt) {
                const int bcol = bt * 16 + row_local;
                #pragma unroll
                for (int fi = 0; fi < MAXA; ++fi) {
                    if (fi < cntA) {
                        int kf = offA + fi;
                        const f16x8* p = (LAYER == 0)
                            ? (const f16x8*)(srcin + (size_t)bcol * 64 + kf * 32 + kg8)
                            : (const f16x8*)(srcin + (size_t)bcol * TWOH + kf * 32 + kg8);
                        acc2[bt] = __builtin_amdgcn_mfma_f32_16x16x32_f16(aregA[fi], *p, acc2[bt], 0, 0, 0);
                    }
                }
            }
        }

        if (tid == 0) {
            const unsigned tgt = (unsigned)GSIZE * (unsigned)(s + 1);
            while (__hip_atomic_load(mybar, __ATOMIC_RELAXED, __HIP_MEMORY_SCOPE_AGENT) < tgt)
                __builtin_amdgcn_s_sleep(1);
            __builtin_amdgcn_fence(__ATOMIC_ACQUIRE, "agent");   // inv: see others' h
        }
        __syncthreads();

        // ---- recurrence + finalize ----
        if (do_comp) {
            if (s > 0) {
                const f16* srcrec = (LAYER == 0)
                    ? (h1 + (size_t)(dir ? t + 1 : t - 1) * 51200 + dir * HID)
                    : (ring + ((size_t)((s - 1) & 3) * 2 + dir) * 25600);
                #pragma unroll
                for (int bt = 0; bt < 2; ++bt) {
                    const int bcol = bt * 16 + row_local;
                    #pragma unroll
                    for (int fi = 0; fi < MAXB; ++fi) {
                        if (fi < cntB) {
                            int kf = offB + fi;
                            const f16x8* p = (LAYER == 0)
                                ? (const f16x8*)(srcrec + (size_t)bcol * TWOH + kf * 32 + kg8)
                                : (const f16x8*)(srcrec + (size_t)bcol * HID + kf * 32 + kg8);
                            acc2[bt] = __builtin_amdgcn_mfma_f32_16x16x32_f16(aregB[fi], *p, acc2[bt], 0, 0, 0);
                        }
                    }
                }
            }
            #pragma unroll
            for (int bt = 0; bt < 2; ++bt)
                #pragma unroll
                for (int r = 0; r < 4; ++r)
                    lds_part[wid][bt][(lane >> 4) * 4 + r][row_local] = acc2[bt][r];
        }
        __syncthreads();
        if (do_comp) {
            #pragma unroll
            for (int i = 0; i < 2; ++i) {
                int idx = tid + i * 512;
                int b = idx & 31, row = (idx >> 5) & 15, tile = idx >> 9;
                float sum = biasreg[i];
                #pragma unroll
                for (int k2 = 0; k2 < 4; ++k2)
                    sum += lds_part[tile * 4 + k2][b >> 4][row][b & 15];
                lds_pre[tile][row][b] = sum;
            }
        }
        __syncthreads();
        if (do_comp && tid < TPB * 128) {
            int tile = tid >> 7, jl_ = (tid >> 5) & 3, b = tid & 31;
            float gi = sigm(lds_pre[tile][jl_][b]);
            float gf = sigm(lds_pre[tile][4 + jl_][b]);
            float gg = tanh_(lds_pre[tile][8 + jl_][b]);
            float go = sigm(lds_pre[tile][12 + jl_][b]);
            float c = gf * lds_c[tile][jl_][b] + gi * gg;
            lds_c[tile][jl_][b] = c;
            lds_h[tile * 4 + jl_][b] = (f16)(go * tanh_(c));
        }
        __syncthreads();
        if (do_comp && tid < 32) {
            f16x8 v;
            #pragma unroll
            for (int e = 0; e < 8; ++e) v[e] = lds_h[e][tid];
            f16* dst = (LAYER == 0)
                ? h1 + (size_t)t * 51200 + (size_t)tid * TWOH + dir * HID + tb * 8
                : ring + ((size_t)(s & 3) * 2 + dir) * 25600 + (size_t)tid * HID + tb * 8;
            *(f16x8*)dst = v;
        }
        // logits blocks: consume ring one step behind (off mains' critical path)
        if (LAYER == 1 && !is_main && s >= 1) {
            const int lb = bid - NMAIN;
            const int tL = dir ? (SEQL - s) : (s - 1);
            const int a = (lb % 5) * 4 + (tid >> 7);
            const int b = (tid >> 2) & 31;
            const int kc = tid & 3;
            const f16* hs = ring + ((size_t)((s - 1) & 3) * 2 + dir) * 25600 + (size_t)b * HID + kc * 200;
            const float* wsrc = Wlin + (size_t)a * TWOH + dir * HID + kc * 200;
            float acc = 0.f;
            #pragma unroll
            for (int q = 0; q < 25; ++q) {
                f16x8 hv = ((const f16x8*)hs)[q];
                #pragma unroll
                for (int e = 0; e < 8; ++e) acc += (float)hv[e] * wsrc[q * 8 + e];
            }
            acc += __shfl_xor(acc, 1);
            acc += __shfl_xor(acc, 2);
            if (kc == 0) logits[(size_t)tL * 640 + a * 32 + b] += acc;
        }
    }
}

// softmax over batch (dim=1) per (l,a); prob-weighted sin/cos -> pts [m][2][32]
__global__ __launch_bounds__(64) void softmax_pts(
    const float* __restrict__ logits, const float* __restrict__ alpha,
    float* __restrict__ pts)
{
    const int l = blockIdx.x;
    const int tid = threadIdx.x;
    const int b = tid & 31;
    float sins[3] = {0.f, 0.f, 0.f}, coss[3] = {0.f, 0.f, 0.f};
    for (int a = 0; a < ALPH; ++a) {
        float v = logits[(size_t)l * 640 + (size_t)a * 32 + b];
        float m = v;
        #pragma unroll
        for (int d = 16; d >= 1; d >>= 1) m = fmaxf(m, __shfl_xor(m, d));
        float e = __expf(v - m);
        float ssum = e;
        #pragma unroll
        for (int d = 16; d >= 1; d >>= 1) ssum += __shfl_xor(ssum, d);
        float pv = e / ssum;
        #pragma unroll
        for (int d = 0; d < 3; ++d) {
            float ang = alpha[a * 3 + d];
            sins[d] += pv * sinf(ang);
            coss[d] += pv * cosf(ang);
        }
    }
    if (tid < 32) {
        const float blen[3] = {145.801f, 152.326f, 132.868f};
        const float bang[3] = {2.124f, 1.941f, 2.028f};
        #pragma unroll
        for (int d = 0; d < 3; ++d) {
            float pa = 3.14159265358979323846f - bang[d];
            float rsin = blen[d] * sinf(pa);
            float sv = sins[d], cv = coss[d];
            float den = sqrtf(sv * sv + cv * cv);
            float cs, sn;
            if (den > 0.f) { cs = cv / den; sn = sv / den; }
            else           { cs = 1.f;     sn = 0.f; }
            size_t m = (size_t)(3 * l + d);
            pts[m * 64 + b]      = cs * rsin;
            pts[m * 64 + 32 + b] = sn * rsin;
        }
    }
}

// NeRF chain: 32 independent batch chains in one wave.
__global__ __launch_bounds__(64) void coords_kernel(
    const float* __restrict__ pts, float* __restrict__ out)
{
    const int tid = threadIdx.x;
    const int b = tid & 31;
    float ax = -0.70710678118654752f, ay = 1.22474487139158905f, az = 0.f;
    float bx = -1.41421356237309505f, by = 0.f, bz = 0.f;
    float cx = 0.f, cy = 0.f, cz = 0.f;
    const float blen[3] = {145.801f, 152.326f, 132.868f};
    const float bang[3] = {2.124f, 1.941f, 2.028f};
    float rcos[3], rb[3];
    #pragma unroll
    for (int d = 0; d < 3; ++d) {
        rcos[d] = blen[d] * cosf(3.14159265358979323846f - bang[d]);
        rb[d] = 1.0f / blen[d];
    }
    int j = 0;
    for (int m = 0; m < 3 * SEQL; ++m) {
        float px = rcos[j];
        float py = pts[(size_t)m * 64 + b];
        float pz = pts[(size_t)m * 64 + 32 + b];
        float ux = cx - bx, uy = cy - by, uz = cz - bz;
        float inv = (m == 0) ? rsqrtf(ux * ux + uy * uy + uz * uz + 1e-12f)
                             : rb[(j + 2) % 3];
        float vx = bx - ax, vy = by - ay, vz = bz - az;
        float nx = vy * uz - vz * uy;
        float ny = vz * ux - vx * uz;
        float nz = vx * uy - vy * ux;
        float inv2 = rsqrtf(nx * nx + ny * ny + nz * nz + 1e-12f);
        nx *= inv2; ny *= inv2; nz *= inv2;
        float mx = ny * uz - nz * uy;
        float my = nz * ux - nx * uz;
        float mz = nx * uy - ny * ux;
        float sx = px * inv, sy = py * inv;
        float ox = cx + ux * sx + mx * sy + nx * pz;
        float oy = cy + uy * sx + my * sy + ny * pz;
        float oz = cz + uz * sx + mz * sy + nz * pz;
        if (tid < 32) {
            float* o = out + ((size_t)m * 32 + b) * 3;
            o[0] = ox; o[1] = oy; o[2] = oz;
        }
        ax = bx; ay = by; az = bz;
        bx = cx; by = cy; bz = cz;
        cx = ox; cy = oy; cz = oz;
        j = (j == 2) ? 0 : j + 1;
    }
}

// ---------------------------------------------------------------------------
extern "C" void kernel_launch(void* const* d_in, const int* in_sizes, int n_in,
                              void* d_out, int out_size, void* d_ws, size_t ws_size,
                              hipStream_t stream)
{
    const float* x     = (const float*)d_in[0];
    const float* Wih0f = (const float*)d_in[1];
    const float* Whh0f = (const float*)d_in[2];
    const float* b0f   = (const float*)d_in[3];
    const float* Wih0r = (const float*)d_in[4];
    const float* Whh0r = (const float*)d_in[5];
    const float* b0r   = (const float*)d_in[6];
    const float* Wih1f = (const float*)d_in[7];
    const float* Whh1f = (const float*)d_in[8];
    const float* b1f   = (const float*)d_in[9];
    const float* Wih1r = (const float*)d_in[10];
    const float* Whh1r = (const float*)d_in[11];
    const float* b1r   = (const float*)d_in[12];
    const float* Wlin  = (const float*)d_in[13];
    const float* blin  = (const float*)d_in[14];
    const float* alpha = (const float*)d_in[15];

    // ws: [bar 1KB pad->256B*4][h1 71,680,000B][region 2,867,200B]
    // region: xT (L0 phase) aliased later by {ring(409,600) logits(1,792,000) pts(537,600)}
    if (ws_size < 74547456ull) return;
    unsigned* bar = (unsigned*)d_ws;
    f16* h1 = (f16*)((char*)d_ws + 1024);
    char* region = (char*)d_ws + 1024 + 71680000ull;
    f16*   xT     = (f16*)region;
    f16*   ring   = (f16*)region;
    float* logits = (float*)(region + 409600);
    float* pts    = (float*)(region + 2201600);

    hipMemsetAsync(bar, 0, 1024, stream);
    transpose_x<<<SEQL, 256, 0, stream>>>(x, xT);
    lstm_phase<0><<<200, 512, 0, stream>>>(
        Wih0f, Wih0r, Whh0f, Whh0r, b0f, b0r,
        xT, h1, ring, logits, Wlin, blin, bar);
    lstm_phase<1><<<210, 512, 0, stream>>>(
        Wih1f, Wih1r, Whh1f, Whh1r, b1f, b1r,
        xT, h1, ring, logits, Wlin, blin, bar);
    softmax_pts<<<SEQL, 64, 0, stream>>>(logits, alpha, pts);
    coords_kernel<<<1, 64, 0, stream>>>(pts, (float*)d_out);
}

// Round 7
// 18249.750 us; speedup vs baseline: 7.5633x; 1.0182x over previous
//
#include <hip/hip_runtime.h>
#include <math.h>

#define HID   800
#define ALPH  20
#define SEQL  700
#define TWOH  1600

typedef _Float16 f16;
typedef _Float16 f16x8 __attribute__((ext_vector_type(8)));
typedef float    f32x4 __attribute__((ext_vector_type(4)));

__device__ __forceinline__ float sigm(float x) { return 1.0f / (1.0f + __expf(-x)); }
__device__ __forceinline__ float tanh_(float x) { return 1.0f - 2.0f / (1.0f + __expf(2.0f * x)); }

// x [B=32][L=700][42] f32  ->  xT [t][b][64] f16 (zero-padded 42->64)
__global__ __launch_bounds__(256) void transpose_x(const float* __restrict__ x,
                                                   f16* __restrict__ xT) {
    const int t = blockIdx.x;
    const int b = threadIdx.x >> 3;
    const int kc = (threadIdx.x & 7) * 8;
    #pragma unroll
    for (int e = 0; e < 8; ++e) {
        int k = kc + e;
        float v = (k < 42) ? x[((size_t)b * SEQL + t) * 42 + k] : 0.f;
        xT[(size_t)t * 2048 + b * 64 + k] = (f16)v;
    }
}

// ---------------------------------------------------------------------------
// Persistent LSTM layer, weight-stationary MFMA.
// Per-dir grid-barrier: release fence -> arrival add on one of 8 sub-counter
// lines (bid&7, 256B apart -> 8x less RMW serialization) -> overlapped
// input-projection MFMAs -> poll (sum of 8 relaxed loads) -> acquire fence.
// 8 waves/block: wave = (tile_sel<1:0>=wid>>2, kw=wid&3). Tile = 16 rows
// (4 j x 4 gates interleaved) x 32 batch. TPB=2 tiles, 4-way K-split.
// LAYER 0: 200 blocks (100/dir); A = x-proj (K=64), B = Whh (K=800).
// LAYER 1: 200 main (100/dir) + 10 logits blocks; A = Wih1 (K=1600),
//          B = Whh (K=800); h kept in 4-slot ring; logits blocks consume
//          ring one step behind (their own overlap slot).
// ---------------------------------------------------------------------------
template <int LAYER>
__global__ __launch_bounds__(512) void lstm_phase(
    const float* __restrict__ Wih_f, const float* __restrict__ Wih_r,
    const float* __restrict__ Whh_f, const float* __restrict__ Whh_r,
    const float* __restrict__ bias_f, const float* __restrict__ bias_r,
    const f16* __restrict__ xT,
    f16* __restrict__ h1,
    f16* __restrict__ ring,
    float* __restrict__ logits,
    const float* __restrict__ Wlin, const float* __restrict__ blin,
    unsigned* __restrict__ bar)
{
    constexpr int TPB   = 2;
    constexpr int BPD   = 100;
    constexpr int NMAIN = 200;
    constexpr int MAXA  = (LAYER == 0) ? 2 : 13;
    constexpr int MAXB  = 7;
    constexpr int GSIZE = (LAYER == 0) ? 100 : 105;
    constexpr int SMAX  = (LAYER == 0) ? 699 : 700;

    __shared__ float lds_part[8][2][16][16];
    __shared__ float lds_pre[TPB][16][32];
    __shared__ float lds_c[TPB][4][32];
    __shared__ f16   lds_h[TPB * 4][32];

    const int bid = blockIdx.x, tid = threadIdx.x;
    const int lane = tid & 63, wid = tid >> 6;
    const bool is_main = (LAYER == 0) || (bid < NMAIN);

    int dir, tb = 0;
    if (is_main) { dir = bid / BPD; tb = bid % BPD; }
    else         { dir = (bid - NMAIN) / 5; }
    // per-(layer,dir) group of 512 u32 (2KB); 8 sub-counter lines at +0..+448
    unsigned* grp   = bar + ((LAYER == 0 ? 0 : 2) + dir) * 512;
    unsigned* myctr = grp + (bid & 7) * 64;

    const int tile_sel = wid >> 2, kw = wid & 3;
    const int row_local = lane & 15;
    const int kg8 = (lane >> 4) * 8;

    int cntA, offA;
    if constexpr (LAYER == 0) { cntA = (kw == 0) ? 2 : 0; offA = 0; }
    else { cntA = (kw < 2) ? 13 : 12; offA = (kw < 2) ? kw * 13 : 26 + (kw - 2) * 12; }
    const int cntB = (kw == 0) ? 7 : 6;
    const int offB = (kw == 0) ? 0 : 7 + (kw - 1) * 6;

    f16x8 aregA[MAXA];
    f16x8 aregB[MAXB];
    float biasreg[2] = {0.f, 0.f};

    if (is_main) {
        const int gate = row_local >> 2, jl = row_local & 3;
        const int jtile = tb * TPB + tile_sel;
        const int grow = gate * HID + jtile * 4 + jl;
        const float* Wih = dir ? Wih_r : Wih_f;
        const float* Whh = dir ? Whh_r : Whh_f;

        #pragma unroll
        for (int fi = 0; fi < MAXA; ++fi) {
            f16x8 a{};
            if (fi < cntA) {
                int kf = offA + fi;
                if constexpr (LAYER == 0) {
                    int k0 = kf * 32 + kg8;
                    #pragma unroll
                    for (int e = 0; e < 8; ++e)
                        a[e] = (f16)((k0 + e < 42) ? Wih[(size_t)grow * 42 + k0 + e] : 0.f);
                } else {
                    const float* p = Wih + (size_t)grow * TWOH + kf * 32 + kg8;
                    #pragma unroll
                    for (int e = 0; e < 8; ++e) a[e] = (f16)p[e];
                }
            }
            aregA[fi] = a;
        }
        #pragma unroll
        for (int fi = 0; fi < MAXB; ++fi) {
            f16x8 a{};
            if (fi < cntB) {
                const float* p = Whh + (size_t)grow * HID + (offB + fi) * 32 + kg8;
                #pragma unroll
                for (int e = 0; e < 8; ++e) a[e] = (f16)p[e];
            }
            aregB[fi] = a;
        }
        const float* bias = dir ? bias_r : bias_f;
        #pragma unroll
        for (int i = 0; i < 2; ++i) {
            int idx = tid + i * 512;
            int row = (idx >> 5) & 15, tile = idx >> 9;
            biasreg[i] = bias[(row >> 2) * HID + (tb * TPB + tile) * 4 + (row & 3)];
        }
        if (tid < TPB * 128) {
            int tile = tid >> 7, jl_ = (tid >> 5) & 3, b = tid & 31;
            lds_c[tile][jl_][b] = 0.f;
        }
    }
    __syncthreads();

    for (int s = 0; s <= SMAX; ++s) {
        const int t = dir ? (SEQL - 1 - s) : s;
        const bool do_comp = is_main && (LAYER == 0 || s < SEQL);

        // pre-signal: logits base init (must precede arrival #1)
        if (LAYER == 1 && !is_main && s == 0) {
            const int lb = bid - NMAIN;
            for (int idx = lb * 512 + tid; idx < SEQL * 640; idx += 10 * 512)
                logits[idx] = blin[(idx >> 5) % ALPH];
        }
        __syncthreads();   // also drains prev step's h stores (vmcnt)
        if (tid == 0) {
            __builtin_amdgcn_fence(__ATOMIC_RELEASE, "agent");   // wbl2: publish h(s-1)
            __hip_atomic_fetch_add(myctr, 1u, __ATOMIC_RELAXED, __HIP_MEMORY_SCOPE_AGENT);
        }

        // ---- overlapped with other blocks' arrival: input projection ----
        f32x4 acc2[2];
        #pragma unroll
        for (int bt = 0; bt < 2; ++bt) acc2[bt] = {0.f, 0.f, 0.f, 0.f};
        if (do_comp) {
            const f16* srcin = (LAYER == 0) ? (xT + (size_t)t * 2048)
                                            : (h1 + (size_t)t * 51200);
            #pragma unroll
            for (int bt = 0; bt < 2; ++bt) {
                const int bcol = bt * 16 + row_local;
                #pragma unroll
                for (int fi = 0; fi < MAXA; ++fi) {
                    if (fi < cntA) {
                        int kf = offA + fi;
                        const f16x8* p = (LAYER == 0)
                            ? (const f16x8*)(srcin + (size_t)bcol * 64 + kf * 32 + kg8)
                            : (const f16x8*)(srcin + (size_t)bcol * TWOH + kf * 32 + kg8);
                        acc2[bt] = __builtin_amdgcn_mfma_f32_16x16x32_f16(aregA[fi], *p, acc2[bt], 0, 0, 0);
                    }
                }
            }
        }

        if (tid == 0) {
            const unsigned tgt = (unsigned)GSIZE * (unsigned)(s + 1);
            for (;;) {
                unsigned c = 0;
                #pragma unroll
                for (int q = 0; q < 8; ++q)
                    c += __hip_atomic_load(grp + q * 64, __ATOMIC_RELAXED, __HIP_MEMORY_SCOPE_AGENT);
                if (c >= tgt) break;
                __builtin_amdgcn_s_sleep(1);
            }
            __builtin_amdgcn_fence(__ATOMIC_ACQUIRE, "agent");   // inv: see others' h
        }
        __syncthreads();

        // ---- recurrence + finalize ----
        if (do_comp) {
            if (s > 0) {
                const f16* srcrec = (LAYER == 0)
                    ? (h1 + (size_t)(dir ? t + 1 : t - 1) * 51200 + dir * HID)
                    : (ring + ((size_t)((s - 1) & 3) * 2 + dir) * 25600);
                #pragma unroll
                for (int bt = 0; bt < 2; ++bt) {
                    const int bcol = bt * 16 + row_local;
                    #pragma unroll
                    for (int fi = 0; fi < MAXB; ++fi) {
                        if (fi < cntB) {
                            int kf = offB + fi;
                            const f16x8* p = (LAYER == 0)
                                ? (const f16x8*)(srcrec + (size_t)bcol * TWOH + kf * 32 + kg8)
                                : (const f16x8*)(srcrec + (size_t)bcol * HID + kf * 32 + kg8);
                            acc2[bt] = __builtin_amdgcn_mfma_f32_16x16x32_f16(aregB[fi], *p, acc2[bt], 0, 0, 0);
                        }
                    }
                }
            }
            #pragma unroll
            for (int bt = 0; bt < 2; ++bt)
                #pragma unroll
                for (int r = 0; r < 4; ++r)
                    lds_part[wid][bt][(lane >> 4) * 4 + r][row_local] = acc2[bt][r];
        }
        __syncthreads();
        if (do_comp) {
            #pragma unroll
            for (int i = 0; i < 2; ++i) {
                int idx = tid + i * 512;
                int b = idx & 31, row = (idx >> 5) & 15, tile = idx >> 9;
                float sum = biasreg[i];
                #pragma unroll
                for (int k2 = 0; k2 < 4; ++k2)
                    sum += lds_part[tile * 4 + k2][b >> 4][row][b & 15];
                lds_pre[tile][row][b] = sum;
            }
        }
        __syncthreads();
        if (do_comp && tid < TPB * 128) {
            int tile = tid >> 7, jl_ = (tid >> 5) & 3, b = tid & 31;
            float gi = sigm(lds_pre[tile][jl_][b]);
            float gf = sigm(lds_pre[tile][4 + jl_][b]);
            float gg = tanh_(lds_pre[tile][8 + jl_][b]);
            float go = sigm(lds_pre[tile][12 + jl_][b]);
            float c = gf * lds_c[tile][jl_][b] + gi * gg;
            lds_c[tile][jl_][b] = c;
            lds_h[tile * 4 + jl_][b] = (f16)(go * tanh_(c));
        }
        __syncthreads();
        if (do_comp && tid < 32) {
            f16x8 v;
            #pragma unroll
            for (int e = 0; e < 8; ++e) v[e] = lds_h[e][tid];
            f16* dst = (LAYER == 0)
                ? h1 + (size_t)t * 51200 + (size_t)tid * TWOH + dir * HID + tb * 8
                : ring + ((size_t)(s & 3) * 2 + dir) * 25600 + (size_t)tid * HID + tb * 8;
            *(f16x8*)dst = v;
        }
        // logits blocks: consume ring one step behind (off mains' critical path)
        if (LAYER == 1 && !is_main && s >= 1) {
            const int lb = bid - NMAIN;
            const int tL = dir ? (SEQL - s) : (s - 1);
            const int a = (lb % 5) * 4 + (tid >> 7);
            const int b = (tid >> 2) & 31;
            const int kc = tid & 3;
            const f16* hs = ring + ((size_t)((s - 1) & 3) * 2 + dir) * 25600 + (size_t)b * HID + kc * 200;
            const float* wsrc = Wlin + (size_t)a * TWOH + dir * HID + kc * 200;
            float acc = 0.f;
            #pragma unroll
            for (int q = 0; q < 25; ++q) {
                f16x8 hv = ((const f16x8*)hs)[q];
                #pragma unroll
                for (int e = 0; e < 8; ++e) acc += (float)hv[e] * wsrc[q * 8 + e];
            }
            acc += __shfl_xor(acc, 1);
            acc += __shfl_xor(acc, 2);
            if (kc == 0) logits[(size_t)tL * 640 + a * 32 + b] += acc;
        }
    }
}

// softmax over batch (dim=1) per (l,a); prob-weighted sin/cos -> pts [m][2][32]
__global__ __launch_bounds__(64) void softmax_pts(
    const float* __restrict__ logits, const float* __restrict__ alpha,
    float* __restrict__ pts)
{
    const int l = blockIdx.x;
    const int tid = threadIdx.x;
    const int b = tid & 31;
    float sins[3] = {0.f, 0.f, 0.f}, coss[3] = {0.f, 0.f, 0.f};
    for (int a = 0; a < ALPH; ++a) {
        float v = logits[(size_t)l * 640 + (size_t)a * 32 + b];
        float m = v;
        #pragma unroll
        for (int d = 16; d >= 1; d >>= 1) m = fmaxf(m, __shfl_xor(m, d));
        float e = __expf(v - m);
        float ssum = e;
        #pragma unroll
        for (int d = 16; d >= 1; d >>= 1) ssum += __shfl_xor(ssum, d);
        float pv = e / ssum;
        #pragma unroll
        for (int d = 0; d < 3; ++d) {
            float ang = alpha[a * 3 + d];
            sins[d] += pv * sinf(ang);
            coss[d] += pv * cosf(ang);
        }
    }
    if (tid < 32) {
        const float blen[3] = {145.801f, 152.326f, 132.868f};
        const float bang[3] = {2.124f, 1.941f, 2.028f};
        #pragma unroll
        for (int d = 0; d < 3; ++d) {
            float pa = 3.14159265358979323846f - bang[d];
            float rsin = blen[d] * sinf(pa);
            float sv = sins[d], cv = coss[d];
            float den = sqrtf(sv * sv + cv * cv);
            float cs, sn;
            if (den > 0.f) { cs = cv / den; sn = sv / den; }
            else           { cs = 1.f;     sn = 0.f; }
            size_t m = (size_t)(3 * l + d);
            pts[m * 64 + b]      = cs * rsin;
            pts[m * 64 + 32 + b] = sn * rsin;
        }
    }
}

// NeRF chain: 32 independent batch chains in one wave.
__global__ __launch_bounds__(64) void coords_kernel(
    const float* __restrict__ pts, float* __restrict__ out)
{
    const int tid = threadIdx.x;
    const int b = tid & 31;
    float ax = -0.70710678118654752f, ay = 1.22474487139158905f, az = 0.f;
    float bx = -1.41421356237309505f, by = 0.f, bz = 0.f;
    float cx = 0.f, cy = 0.f, cz = 0.f;
    const float blen[3] = {145.801f, 152.326f, 132.868f};
    const float bang[3] = {2.124f, 1.941f, 2.028f};
    float rcos[3], rb[3];
    #pragma unroll
    for (int d = 0; d < 3; ++d) {
        rcos[d] = blen[d] * cosf(3.14159265358979323846f - bang[d]);
        rb[d] = 1.0f / blen[d];
    }
    int j = 0;
    for (int m = 0; m < 3 * SEQL; ++m) {
        float px = rcos[j];
        float py = pts[(size_t)m * 64 + b];
        float pz = pts[(size_t)m * 64 + 32 + b];
        float ux = cx - bx, uy = cy - by, uz = cz - bz;
        float inv = (m == 0) ? rsqrtf(ux * ux + uy * uy + uz * uz + 1e-12f)
                             : rb[(j + 2) % 3];
        float vx = bx - ax, vy = by - ay, vz = bz - az;
        float nx = vy * uz - vz * uy;
        float ny = vz * ux - vx * uz;
        float nz = vx * uy - vy * ux;
        float inv2 = rsqrtf(nx * nx + ny * ny + nz * nz + 1e-12f);
        nx *= inv2; ny *= inv2; nz *= inv2;
        float mx = ny * uz - nz * uy;
        float my = nz * ux - nx * uz;
        float mz = nx * uy - ny * ux;
        float sx = px * inv, sy = py * inv;
        float ox = cx + ux * sx + mx * sy + nx * pz;
        float oy = cy + uy * sx + my * sy + ny * pz;
        float oz = cz + uz * sx + mz * sy + nz * pz;
        if (tid < 32) {
            float* o = out + ((size_t)m * 32 + b) * 3;
            o[0] = ox; o[1] = oy; o[2] = oz;
        }
        ax = bx; ay = by; az = bz;
        bx = cx; by = cy; bz = cz;
        cx = ox; cy = oy; cz = oz;
        j = (j == 2) ? 0 : j + 1;
    }
}

// ---------------------------------------------------------------------------
extern "C" void kernel_launch(void* const* d_in, const int* in_sizes, int n_in,
                              void* d_out, int out_size, void* d_ws, size_t ws_size,
                              hipStream_t stream)
{
    const float* x     = (const float*)d_in[0];
    const float* Wih0f = (const float*)d_in[1];
    const float* Whh0f = (const float*)d_in[2];
    const float* b0f   = (const float*)d_in[3];
    const float* Wih0r = (const float*)d_in[4];
    const float* Whh0r = (const float*)d_in[5];
    const float* b0r   = (const float*)d_in[6];
    const float* Wih1f = (const float*)d_in[7];
    const float* Whh1f = (const float*)d_in[8];
    const float* b1f   = (const float*)d_in[9];
    const float* Wih1r = (const float*)d_in[10];
    const float* Whh1r = (const float*)d_in[11];
    const float* b1r   = (const float*)d_in[12];
    const float* Wlin  = (const float*)d_in[13];
    const float* blin  = (const float*)d_in[14];
    const float* alpha = (const float*)d_in[15];

    // ws: [bar 8KB (4 groups x 2KB)][h1 71,680,000B][region 2,867,200B]
    // region: xT (L0 phase) aliased later by {ring(409,600) logits(1,792,000) pts(537,600)}
    if (ws_size < 74555392ull) return;
    unsigned* bar = (unsigned*)d_ws;
    f16* h1 = (f16*)((char*)d_ws + 8192);
    char* region = (char*)d_ws + 8192 + 71680000ull;
    f16*   xT     = (f16*)region;
    f16*   ring   = (f16*)region;
    float* logits = (float*)(region + 409600);
    float* pts    = (float*)(region + 2201600);

    hipMemsetAsync(bar, 0, 8192, stream);
    transpose_x<<<SEQL, 256, 0, stream>>>(x, xT);
    lstm_phase<0><<<200, 512, 0, stream>>>(
        Wih0f, Wih0r, Whh0f, Whh0r, b0f, b0r,
        xT, h1, ring, logits, Wlin, blin, bar);
    lstm_phase<1><<<210, 512, 0, stream>>>(
        Wih1f, Wih1r, Whh1f, Whh1r, b1f, b1r,
        xT, h1, ring, logits, Wlin, blin, bar);
    softmax_pts<<<SEQL, 64, 0, stream>>>(logits, alpha, pts);
    coords_kernel<<<1, 64, 0, stream>>>(pts, (float*)d_out);
}